// Round 9
// baseline (5756.257 us; speedup 1.0000x reference)
//
#include <hip/hip_runtime.h>
#include <hip/hip_bf16.h>

#define WN 32768
#define LN 16
#define DN 128
#define WLN (WN * LN)        // 524288
#define NNODES 50000
#define FHN 384

typedef __attribute__((ext_vector_type(8))) short short8;
typedef __attribute__((ext_vector_type(4))) float float4v;
typedef __hip_bfloat16 bf16;

__device__ __forceinline__ unsigned fenc(float f) {
  unsigned u = __float_as_uint(f);
  return (u & 0x80000000u) ? ~u : (u | 0x80000000u);
}
__device__ __forceinline__ float fdec(unsigned u) {
  unsigned v = (u & 0x80000000u) ? (u & 0x7FFFFFFFu) : ~u;
  return __uint_as_float(v);
}
// fast transcendentals: v_exp + v_rcp (~1e-5 rel err, far below bf16 granularity)
__device__ __forceinline__ float sigm(float x) {
  return __builtin_amdgcn_rcpf(1.f + __expf(-x));
}
__device__ __forceinline__ float ftanh(float x) {
  return 1.f - 2.f * __builtin_amdgcn_rcpf(1.f + __expf(2.f * x));
}

// ---------- weight prep ----------
// Wcat2 [512][256]: rows 0..127 r:[wi|wh], 128..255 z:[wi|wh], 256..383 xn:[wi|0], 384..511 hn:[0|wh]
__global__ __launch_bounds__(256) void wcat2_k(const float* __restrict__ wi,
                                               const float* __restrict__ wh,
                                               bf16* __restrict__ W) {
  int idx = blockIdx.x * 256 + threadIdx.x;  // 512*256
  int n2 = idx >> 8, k2 = idx & 255;
  float v;
  if (n2 < 256)      v = (k2 < 128) ? wi[n2 * 128 + k2] : wh[n2 * 128 + (k2 - 128)];
  else if (n2 < 384) v = (k2 < 128) ? wi[n2 * 128 + k2] : 0.f;
  else               v = (k2 < 128) ? 0.f : wh[(n2 - 128) * 128 + (k2 - 128)];
  W[idx] = (bf16)v;
}

__global__ __launch_bounds__(256) void conv2d_k(const float* __restrict__ src, int ld,
                                                bf16* __restrict__ dst, int cols, int total) {
  int idx = blockIdx.x * 256 + threadIdx.x;
  if (idx >= total) return;
  int r = idx / cols, c = idx - r * cols;
  dst[idx] = (bf16)src[(size_t)r * ld + c];
}

// ---------- RMSNorm -> bf16 ----------
__global__ __launch_bounds__(256) void rmsnorm_bf16_k(const float* __restrict__ X,
                                                      const float* __restrict__ w,
                                                      bf16* __restrict__ out) {
  long row = (long)blockIdx.x * 4 + (threadIdx.x >> 6);
  int lane = threadIdx.x & 63;
  const float* x = X + row * 128;
  float v0 = x[lane], v1 = x[lane + 64];
  float ss = v0 * v0 + v1 * v1;
#pragma unroll
  for (int off = 32; off > 0; off >>= 1) ss += __shfl_down(ss, off);
  ss = __shfl(ss, 0);
  float r = rsqrtf(ss * (1.f / 128.f) + 1e-5f);
  out[row * 128 + lane] = (bf16)(v0 * r * w[lane]);
  out[row * 128 + lane + 64] = (bf16)(v1 * r * w[lane + 64]);
}

// ---------- fused gather-add + RMSNorm (iter-2 boundary) ----------
__global__ __launch_bounds__(256) void rmsnorm_gather_k(float* __restrict__ X,
                                                        const float* __restrict__ back,
                                                        const int* __restrict__ seg,
                                                        const float* __restrict__ w,
                                                        bf16* __restrict__ out) {
  long row = (long)blockIdx.x * 4 + (threadIdx.x >> 6);
  int lane = threadIdx.x & 63;
  int s = seg[row];
  float v0 = X[row * 128 + lane] + back[(long)s * 128 + lane];
  float v1 = X[row * 128 + lane + 64] + back[(long)s * 128 + lane + 64];
  X[row * 128 + lane] = v0;
  X[row * 128 + lane + 64] = v1;
  float ss = v0 * v0 + v1 * v1;
#pragma unroll
  for (int off = 32; off > 0; off >>= 1) ss += __shfl_down(ss, off);
  ss = __shfl(ss, 0);
  float r = rsqrtf(ss * (1.f / 128.f) + 1e-5f);
  out[row * 128 + lane] = (bf16)(v0 * r * w[lane]);
  out[row * 128 + lane + 64] = (bf16)(v1 * r * w[lane + 64]);
}

// ---------- persistent GRU scan: one launch runs all 16 timesteps ----------
// 512 thr = 8 waves; block owns 64 walks; state lives in LDS; B lives in VGPRs.
// Wave w, j in 0..3: column-tile ct = w + 8*j -> gate j (r,z,xn,hn), cols d = w*16 + (lane&15).
// Gate xn only uses k<128 (x part); hn only k>=128 (h part) -> those MFMAs are pruned.
__global__ __launch_bounds__(512, 2) void gru_seq_k(const bf16* __restrict__ hbase,  // [WLN][128]
                                                    bf16* __restrict__ yhist,        // [WLN][128]
                                                    const bf16* __restrict__ W,      // [512][256]
                                                    const float* __restrict__ bi,
                                                    const float* __restrict__ bh,
                                                    int reverse) {
  __shared__ __attribute__((aligned(16))) bf16 Ac[64][280];   // cols 0..127 x(t), 128..255 h, pad->2-way banks
  __shared__ __attribute__((aligned(16))) bf16 Bst[512][40];  // preamble staging only
  const int tid = threadIdx.x;
  const int w = tid >> 6, lane = tid & 63;
  const int c = lane & 15, qd = lane >> 4;
  const long rb = (long)blockIdx.x * 64;

  // ---- preload B fragments into registers (skip structurally-zero blocks) ----
  short8 breg[4][8];
#pragma unroll
  for (int kc = 0; kc < 8; ++kc) {
#pragma unroll
    for (int i = 0; i < 8; i++) {
      int q = tid + i * 512;
      int row = q >> 3, kq = (q & 7) * 4;
      *(ushort4*)&Bst[row][kq] = *(const ushort4*)(W + (size_t)row * 256 + kc * 32 + kq);
    }
    __syncthreads();
#pragma unroll
    for (int j = 0; j < 4; j++) {
      if ((j == 2 && kc >= 4) || (j == 3 && kc < 4)) continue;  // zero blocks
      breg[j][kc] = *(const short8*)&Bst[(w + 8 * j) * 16 + c][qd * 8];
    }
    __syncthreads();
  }

  // per-thread fixed output column d and its biases
  const int d = w * 16 + c;
  const float bR  = bi[d] + bh[d];
  const float bZ  = bi[128 + d] + bh[128 + d];
  const float bXN = bi[256 + d];
  const float bHN = bh[256 + d];

  // zero the state region
#pragma unroll
  for (int i = 0; i < 4; i++) {
    int q = tid + i * 512;
    int row = q >> 5, kq = (q & 31) * 4;
    *(ushort4*)&Ac[row][128 + kq] = make_ushort4(0, 0, 0, 0);
  }

  int lprev = 0;
  for (int t = 0; t < 16; ++t) {
    const int l = reverse ? (15 - t) : t;
    // stage x(l) into Ac[.][0..127]
#pragma unroll
    for (int i = 0; i < 4; i++) {
      int q = tid + i * 512;
      int row = q >> 5, kq = (q & 31) * 4;
      *(ushort4*)&Ac[row][kq] =
          *(const ushort4*)(hbase + ((rb + row) * 16 + l) * 128 + kq);
    }
    __syncthreads();
    // coalesced dump of previous step's hidden state (overlaps with MFMA below)
    if (t > 0) {
#pragma unroll
      for (int i = 0; i < 4; i++) {
        int q = tid + i * 512;
        int row = q >> 5, kq = (q & 31) * 4;
        *(ushort4*)(yhist + ((rb + row) * 16 + lprev) * 128 + kq) =
            *(const ushort4*)&Ac[row][128 + kq];
      }
    }
    float4v acc[4][4];
#pragma unroll
    for (int rt = 0; rt < 4; rt++)
#pragma unroll
      for (int j = 0; j < 4; j++) acc[rt][j] = (float4v)(0.f);
#pragma unroll
    for (int kc = 0; kc < 8; ++kc) {
      const int k0 = kc * 32;
      short8 af[4];
#pragma unroll
      for (int rt = 0; rt < 4; rt++)
        af[rt] = *(const short8*)&Ac[rt * 16 + c][k0 + qd * 8];
#pragma unroll
      for (int rt = 0; rt < 4; rt++) {
#pragma unroll
        for (int j = 0; j < 4; j++) {
          if ((j == 2 && kc >= 4) || (j == 3 && kc < 4)) continue;
          acc[rt][j] = __builtin_amdgcn_mfma_f32_16x16x32_bf16(af[rt], breg[j][kc], acc[rt][j], 0, 0, 0);
        }
      }
    }
    __syncthreads();
    // epilogue: gates -> new state (per-thread-private (row,d) cells)
#pragma unroll
    for (int rt = 0; rt < 4; rt++) {
#pragma unroll
      for (int reg = 0; reg < 4; ++reg) {
        int row = rt * 16 + qd * 4 + reg;
        float r = sigm(acc[rt][0][reg] + bR);
        float z = sigm(acc[rt][1][reg] + bZ);
        float n = ftanh(acc[rt][2][reg] + bXN + r * (acc[rt][3][reg] + bHN));
        float hold = (float)Ac[row][128 + d];
        Ac[row][128 + d] = (bf16)((1.f - z) * n + z * hold);
      }
    }
    lprev = l;
  }
  __syncthreads();
  // dump final step
#pragma unroll
  for (int i = 0; i < 4; i++) {
    int q = tid + i * 512;
    int row = q >> 5, kq = (q & 31) * 4;
    *(ushort4*)(yhist + ((rb + row) * 16 + lprev) * 128 + kq) =
        *(const ushort4*)&Ac[row][128 + kq];
  }
}

// ---------- generic bf16 MFMA GEMM: C[M,128-panel] (+)= A@B^T ----------
// EPI: 0=store, 2=add, 3=add + fused RMSNorm->bf16 (requires grid.y==1, ldc==128)
template <int EPI>
__global__ __launch_bounds__(256, 2) void mm_bf16_k(const bf16* __restrict__ A, int lda,
                                                    const bf16* __restrict__ B, int ldb,
                                                    float* __restrict__ C, int ldc, int K,
                                                    const float* __restrict__ nw,
                                                    bf16* __restrict__ hout) {
  __shared__ __attribute__((aligned(16))) bf16 As[64][40];
  __shared__ __attribute__((aligned(16))) bf16 Bs[128][40];
  const int tid = threadIdx.x;
  const int wave = tid >> 6, lane = tid & 63;
  const long rb = (long)blockIdx.x * 64;
  const int nb = blockIdx.y * 128;
  float4v acc[8];
#pragma unroll
  for (int i = 0; i < 8; i++) acc[i] = (float4v)(0.f);
  for (int k0 = 0; k0 < K; k0 += 32) {
#pragma unroll
    for (int i = 0; i < 2; i++) {
      int q = tid + i * 256;
      int row = q >> 3, kq = (q & 7) * 4;
      *(ushort4*)&As[row][kq] = *(const ushort4*)(A + (rb + row) * (size_t)lda + k0 + kq);
    }
#pragma unroll
    for (int i = 0; i < 4; i++) {
      int q = tid + i * 256;
      int row = q >> 3, kq = (q & 7) * 4;
      *(ushort4*)&Bs[row][kq] = *(const ushort4*)(B + (size_t)(nb + row) * ldb + k0 + kq);
    }
    __syncthreads();
    short8 af = *(const short8*)&As[wave * 16 + (lane & 15)][(lane >> 4) * 8];
#pragma unroll
    for (int ct = 0; ct < 8; ++ct) {
      short8 bf = *(const short8*)&Bs[ct * 16 + (lane & 15)][(lane >> 4) * 8];
      acc[ct] = __builtin_amdgcn_mfma_f32_16x16x32_bf16(af, bf, acc[ct], 0, 0, 0);
    }
    __syncthreads();
  }
  const int c = lane & 15, qd = lane >> 4;
  if (EPI == 3) {
#pragma unroll
    for (int reg = 0; reg < 4; ++reg) {
      long row = rb + wave * 16 + qd * 4 + reg;
      float v[8];
      float ssq = 0.f;
#pragma unroll
      for (int ct = 0; ct < 8; ++ct) {
        int n = ct * 16 + c;
        v[ct] = C[row * 128 + n] + acc[ct][reg];
        ssq += v[ct] * v[ct];
      }
      ssq += __shfl_xor(ssq, 1);
      ssq += __shfl_xor(ssq, 2);
      ssq += __shfl_xor(ssq, 4);
      ssq += __shfl_xor(ssq, 8);
      float rr = rsqrtf(ssq * (1.f / 128.f) + 1e-5f);
#pragma unroll
      for (int ct = 0; ct < 8; ++ct) {
        int n = ct * 16 + c;
        C[row * 128 + n] = v[ct];
        hout[row * 128 + n] = (bf16)(v[ct] * rr * nw[n]);
      }
    }
  } else {
#pragma unroll
    for (int ct = 0; ct < 8; ++ct) {
      int n = nb + ct * 16 + c;
#pragma unroll
      for (int reg = 0; reg < 4; ++reg) {
        long row = rb + wave * 16 + qd * 4 + reg;
        if (EPI == 2) C[row * ldc + n] += acc[ct][reg];
        else C[row * ldc + n] = acc[ct][reg];
      }
    }
  }
}

// ---------- fused SwiGLU gate (bf16 MFMA): U = silu(A@W1^T)*(A@W3^T) ----------
__global__ __launch_bounds__(256, 2) void ffn_gate2_k(const bf16* __restrict__ A,
                                                      const bf16* __restrict__ W13,
                                                      bf16* __restrict__ U) {
  __shared__ __attribute__((aligned(16))) bf16 As[64][40];
  __shared__ __attribute__((aligned(16))) bf16 Bs[256][40];
  const int tid = threadIdx.x;
  const int wave = tid >> 6, lane = tid & 63;
  const long rb = (long)blockIdx.x * 64;
  const int nb = blockIdx.y * 128;
  float4v a1[8], a3[8];
#pragma unroll
  for (int i = 0; i < 8; i++) { a1[i] = (float4v)(0.f); a3[i] = (float4v)(0.f); }
  for (int k0 = 0; k0 < 128; k0 += 32) {
#pragma unroll
    for (int i = 0; i < 2; i++) {
      int q = tid + i * 256;
      int row = q >> 3, kq = (q & 7) * 4;
      *(ushort4*)&As[row][kq] = *(const ushort4*)(A + (rb + row) * 128 + k0 + kq);
    }
#pragma unroll
    for (int i = 0; i < 8; i++) {
      int q = tid + i * 256;
      int row = q >> 3, kq = (q & 7) * 4;
      int srcrow = (row < 128) ? (nb + row) : (384 + nb + row - 128);
      *(ushort4*)&Bs[row][kq] = *(const ushort4*)(W13 + (size_t)srcrow * 128 + k0 + kq);
    }
    __syncthreads();
    short8 af = *(const short8*)&As[wave * 16 + (lane & 15)][(lane >> 4) * 8];
#pragma unroll
    for (int ct = 0; ct < 8; ++ct) {
      short8 b1 = *(const short8*)&Bs[ct * 16 + (lane & 15)][(lane >> 4) * 8];
      a1[ct] = __builtin_amdgcn_mfma_f32_16x16x32_bf16(af, b1, a1[ct], 0, 0, 0);
      short8 b3 = *(const short8*)&Bs[128 + ct * 16 + (lane & 15)][(lane >> 4) * 8];
      a3[ct] = __builtin_amdgcn_mfma_f32_16x16x32_bf16(af, b3, a3[ct], 0, 0, 0);
    }
    __syncthreads();
  }
  const int c = lane & 15, qd = lane >> 4;
#pragma unroll
  for (int ct = 0; ct < 8; ++ct) {
    int d = nb + ct * 16 + c;
#pragma unroll
    for (int reg = 0; reg < 4; ++reg) {
      long row = rb + wave * 16 + qd * 4 + reg;
      float g = a1[ct][reg];
      U[row * 384 + d] = (bf16)(g * sigm(g) * a3[ct][reg]);
    }
  }
}

// ---------- fp32 GEMM (precision-critical small paths) ----------
enum { EPI_STORE = 0, EPI_RELU = 1 };
template <int EPI>
__global__ __launch_bounds__(256) void gemm_k(const float* __restrict__ A, int lda,
                                              const float* __restrict__ B, int ldb,
                                              const float* __restrict__ bias,
                                              float* __restrict__ C, int ldc,
                                              int M, int N, int K) {
  __shared__ float As[16][68];
  __shared__ float Bs[16][68];
  const int tid = threadIdx.x;
  const int bm = blockIdx.x * 64;
  const int bn = blockIdx.y * 64;
  const int lm = tid >> 2;
  const int lk = (tid & 3) << 2;
  const int tm = (tid >> 4) << 2;
  const int tn = (tid & 15) << 2;
  float acc[4][4] = {};
  for (int k0 = 0; k0 < K; k0 += 16) {
    float4 av = make_float4(0.f, 0.f, 0.f, 0.f);
    if (bm + lm < M)
      av = *reinterpret_cast<const float4*>(A + (long)(bm + lm) * lda + k0 + lk);
    As[lk + 0][lm] = av.x; As[lk + 1][lm] = av.y; As[lk + 2][lm] = av.z; As[lk + 3][lm] = av.w;
    float4 bv = *reinterpret_cast<const float4*>(B + (long)(bn + lm) * ldb + k0 + lk);
    Bs[lk + 0][lm] = bv.x; Bs[lk + 1][lm] = bv.y; Bs[lk + 2][lm] = bv.z; Bs[lk + 3][lm] = bv.w;
    __syncthreads();
#pragma unroll
    for (int k = 0; k < 16; k++) {
      float a[4], b[4];
#pragma unroll
      for (int j = 0; j < 4; j++) { a[j] = As[k][tm + j]; b[j] = Bs[k][tn + j]; }
#pragma unroll
      for (int i = 0; i < 4; i++)
#pragma unroll
        for (int j = 0; j < 4; j++) acc[i][j] = fmaf(a[i], b[j], acc[i][j]);
    }
    __syncthreads();
  }
#pragma unroll
  for (int i = 0; i < 4; i++) {
    int gm = bm + tm + i;
    if (gm < M) {
      float* crow = C + (long)gm * ldc + bn;
#pragma unroll
      for (int j = 0; j < 4; j++) {
        float v = acc[i][j] + (bias ? bias[bn + tn + j] : 0.f);
        if (EPI == EPI_RELU) v = fmaxf(v, 0.f);
        crow[tn + j] = v;
      }
    }
  }
}

// ---------- to_node GEMM (fp32) fused with attention scatter ----------
__global__ __launch_bounds__(256) void tonode_scatter_k(const float* __restrict__ A,
                                                        const float* __restrict__ B,
                                                        const float* __restrict__ bias,
                                                        const float* __restrict__ e,
                                                        const float* __restrict__ denom,
                                                        const int* __restrict__ seg,
                                                        float* __restrict__ node_emb) {
  __shared__ float As[16][68];
  __shared__ float Bs[16][68];
  const int tid = threadIdx.x;
  const long bm = (long)blockIdx.x * 64;
  const int bn = blockIdx.y * 64;
  const int lm = tid >> 2;
  const int lk = (tid & 3) << 2;
  const int tm = (tid >> 4) << 2;
  const int tn = (tid & 15) << 2;
  float acc[4][4] = {};
  for (int k0 = 0; k0 < 128; k0 += 16) {
    float4 av = *reinterpret_cast<const float4*>(A + (bm + lm) * 128 + k0 + lk);
    As[lk + 0][lm] = av.x; As[lk + 1][lm] = av.y; As[lk + 2][lm] = av.z; As[lk + 3][lm] = av.w;
    float4 bv = *reinterpret_cast<const float4*>(B + (long)(bn + lm) * 128 + k0 + lk);
    Bs[lk + 0][lm] = bv.x; Bs[lk + 1][lm] = bv.y; Bs[lk + 2][lm] = bv.z; Bs[lk + 3][lm] = bv.w;
    __syncthreads();
#pragma unroll
    for (int k = 0; k < 16; k++) {
      float a[4], b[4];
#pragma unroll
      for (int j = 0; j < 4; j++) { a[j] = As[k][tm + j]; b[j] = Bs[k][tn + j]; }
#pragma unroll
      for (int i = 0; i < 4; i++)
#pragma unroll
        for (int j = 0; j < 4; j++) acc[i][j] = fmaf(a[i], b[j], acc[i][j]);
    }
    __syncthreads();
  }
#pragma unroll
  for (int i = 0; i < 4; i++) {
    long row = bm + tm + i;
    int s = seg[row];
#pragma unroll
    for (int j = 0; j < 4; j++) {
      int d = bn + tn + j;
      int hh = d >> 4;
      float a = e[row * 8 + hh] / (denom[(long)s * 8 + hh] + 1e-9f);
      atomicAdd(&node_emb[(long)s * 128 + d], a * (acc[i][j] + bias[d]));
    }
  }
}

// ---------- attention pointwise ----------
__global__ __launch_bounds__(256) void logits_k(const float* __restrict__ X,
                                                const float* __restrict__ LW,
                                                const float* __restrict__ LB,
                                                float* __restrict__ out) {
  __shared__ float w[1024];
  __shared__ float b[8];
  int tid = threadIdx.x;
  for (int i = tid; i < 1024; i += 256) w[i] = LW[i];
  if (tid < 8) b[tid] = LB[tid];
  __syncthreads();
  long r = (long)blockIdx.x * 32 + (tid >> 3);
  int hh = tid & 7;
  const float* x = X + r * 128;
  const float* wr = w + hh * 128;
  float s = 0.f;
#pragma unroll 16
  for (int k = 0; k < 128; k++) s = fmaf(x[k], wr[k], s);
  out[r * 8 + hh] = s + b[hh];
}

__global__ __launch_bounds__(256) void segmax_k(const float* __restrict__ logits,
                                                const int* __restrict__ seg,
                                                unsigned* __restrict__ menc) {
  long idx = (long)blockIdx.x * 256 + threadIdx.x;
  long i = idx >> 3;
  int hh = idx & 7;
  atomicMax(&menc[(long)seg[i] * 8 + hh], fenc(logits[idx]));
}

__global__ __launch_bounds__(256) void expdenom_k(float* __restrict__ e_or_logits,
                                                  const int* __restrict__ seg,
                                                  const unsigned* __restrict__ menc,
                                                  float* __restrict__ denom) {
  long idx = (long)blockIdx.x * 256 + threadIdx.x;
  long i = idx >> 3;
  int hh = idx & 7;
  int s = seg[i];
  float ev = expf(e_or_logits[idx] - fdec(menc[(long)s * 8 + hh]));
  e_or_logits[idx] = ev;
  atomicAdd(&denom[(long)s * 8 + hh], ev);
}

__global__ __launch_bounds__(256) void head3_k(const float* __restrict__ H2,
                                               const float* __restrict__ W3,
                                               const float* __restrict__ B3,
                                               float* __restrict__ out, int M) {
  int row = blockIdx.x * 4 + (threadIdx.x >> 6);
  int lane = threadIdx.x & 63;
  if (row >= M) return;
  const float* x = H2 + (long)row * 128;
  float s = x[lane] * W3[lane] + x[lane + 64] * W3[lane + 64];
#pragma unroll
  for (int off = 32; off > 0; off >>= 1) s += __shfl_down(s, off);
  if (lane == 0) out[row] = s + B3[0];
}

// ---------- host ----------
extern "C" void kernel_launch(void* const* d_in, const int* in_sizes, int n_in,
                              void* d_out, int out_size, void* d_ws, size_t ws_size,
                              hipStream_t stream) {
  (void)in_sizes; (void)n_in; (void)out_size; (void)ws_size;
  const float* in_x       = (const float*)d_in[0];
  const int*   seg        = (const int*)d_in[1];
  const float* gru_norm_w = (const float*)d_in[3];
  const float* wi_f       = (const float*)d_in[4];
  const float* wh_f       = (const float*)d_in[5];
  const float* bi_f       = (const float*)d_in[6];
  const float* bh_f       = (const float*)d_in[7];
  const float* wi_b       = (const float*)d_in[8];
  const float* wh_b       = (const float*)d_in[9];
  const float* bi_b       = (const float*)d_in[10];
  const float* bh_b       = (const float*)d_in[11];
  const float* gru_out_w  = (const float*)d_in[12];
  const float* ffn_norm_w = (const float*)d_in[13];
  const float* ffn_w1     = (const float*)d_in[14];
  const float* ffn_w2     = (const float*)d_in[15];
  const float* ffn_w3     = (const float*)d_in[16];
  const float* logit_w    = (const float*)d_in[17];
  const float* logit_b    = (const float*)d_in[18];
  const float* to_node_w  = (const float*)d_in[19];
  const float* to_node_b  = (const float*)d_in[20];
  const float* from_node_w= (const float*)d_in[21];
  const float* from_node_b= (const float*)d_in[22];
  const float* head_w1    = (const float*)d_in[23];
  const float* head_b1    = (const float*)d_in[24];
  const float* head_w2    = (const float*)d_in[25];
  const float* head_b2    = (const float*)d_in[26];
  const float* head_w3    = (const float*)d_in[27];
  const float* head_b3    = (const float*)d_in[28];
  float* out = (float*)d_out;

  // ---- workspace carve-up (float slots), ~589 MB total ----
  float* ws = (float*)d_ws;
  size_t o = 0;
  auto alloc = [&](size_t n) { float* p = ws + o; o += (n + 63) & ~(size_t)63; return p; };
  float* xbuf = alloc((size_t)WLN * 128);   // 268.4 MB fp32 x
  bf16*  hb16 = (bf16*)alloc((size_t)WLN * 64); // 134.2 MB bf16 normed-x
  float* pool = alloc((size_t)WLN * 64);    // 134.2 MB time-shared pool
  // pool phase A (GRU): yhist [WLN][128] bf16
  bf16* yhist = (bf16*)pool;
  // pool phase B (FFN+attention): ub16 | ebuf | menc | denomb
  bf16*     ub16   = (bf16*)pool;                               // 65536*384 bf16 = 50.3 MB
  float*    ebuf   = pool + (size_t)65536 * 384 / 2;            // WLN*8 fp32
  unsigned* menc   = (unsigned*)(ebuf + (size_t)WLN * 8);       // NNODES*8
  float*    denomb = (float*)(menc + (size_t)NNODES * 8);       // NNODES*8
  // pool phase C (post-loop head): h1b | h2b
  float* h1b = pool;
  float* h2b = pool + (size_t)NNODES * 128;
  float* node_emb = alloc((size_t)NNODES * 128);  // survives into head
  float* backb    = alloc((size_t)NNODES * 128);  // survives it0->it1 boundary
  bf16* Wcat2_f = (bf16*)alloc(512 * 256 / 2);
  bf16* Wcat2_b = (bf16*)alloc(512 * 256 / 2);
  bf16* WoF     = (bf16*)alloc(128 * 128 / 2);
  bf16* WoB     = (bf16*)alloc(128 * 128 / 2);
  bf16* W13     = (bf16*)alloc(768 * 128 / 2);
  bf16* W2b     = (bf16*)alloc(128 * 384 / 2);

  // ---- weight conversion ----
  hipLaunchKernelGGL(wcat2_k, dim3(512), dim3(256), 0, stream, wi_f, wh_f, Wcat2_f);
  hipLaunchKernelGGL(wcat2_k, dim3(512), dim3(256), 0, stream, wi_b, wh_b, Wcat2_b);
  hipLaunchKernelGGL(conv2d_k, dim3(64), dim3(256), 0, stream, gru_out_w, 256, WoF, 128, 128 * 128);
  hipLaunchKernelGGL(conv2d_k, dim3(64), dim3(256), 0, stream, gru_out_w + 128, 256, WoB, 128, 128 * 128);
  hipLaunchKernelGGL(conv2d_k, dim3(192), dim3(256), 0, stream, ffn_w1, 128, W13, 128, 384 * 128);
  hipLaunchKernelGGL(conv2d_k, dim3(192), dim3(256), 0, stream, ffn_w3, 128, W13 + 384 * 128, 128, 384 * 128);
  hipLaunchKernelGGL(conv2d_k, dim3(192), dim3(256), 0, stream, ffn_w2, 384, W2b, 384, 128 * 384);

  hipMemcpyAsync(xbuf, in_x, (size_t)WLN * 128 * 4, hipMemcpyDeviceToDevice, stream);

  for (int it = 0; it < 2; ++it) {
    // --- GRU block: RMSNorm (iter-2: fused gather-add of prior back-projection) ---
    if (it == 0)
      hipLaunchKernelGGL(rmsnorm_bf16_k, dim3(WLN / 4), dim3(256), 0, stream, xbuf, gru_norm_w, hb16);
    else
      hipLaunchKernelGGL(rmsnorm_gather_k, dim3(WLN / 4), dim3(256), 0, stream, xbuf, backb, seg, gru_norm_w, hb16);
    // persistent scan, forward; then deferred output projection
    hipLaunchKernelGGL(gru_seq_k, dim3(WN / 64), dim3(512), 0, stream,
                       hb16, yhist, Wcat2_f, bi_f, bh_f, 0);
    hipLaunchKernelGGL((mm_bf16_k<2>), dim3(WLN / 64, 1), dim3(256), 0, stream,
                       yhist, 128, WoF, 128, xbuf, 128, 128, (const float*)nullptr, (bf16*)nullptr);
    // backward scan; projection fused with FFN RMSNorm
    hipLaunchKernelGGL(gru_seq_k, dim3(WN / 64), dim3(512), 0, stream,
                       hb16, yhist, Wcat2_b, bi_b, bh_b, 1);
    hipLaunchKernelGGL((mm_bf16_k<3>), dim3(WLN / 64, 1), dim3(256), 0, stream,
                       yhist, 128, WoB, 128, xbuf, 128, 128, ffn_norm_w, hb16);

    // --- FFN (8 chunks of 65536 rows) ---
    for (int c = 0; c < 8; ++c) {
      const int CM = WLN / 8;
      hipLaunchKernelGGL(ffn_gate2_k, dim3(CM / 64, 3), dim3(256), 0, stream,
                         hb16 + (size_t)c * CM * 128, W13, ub16);
      hipLaunchKernelGGL((mm_bf16_k<2>), dim3(CM / 64, 1), dim3(256), 0, stream,
                         ub16, 384, W2b, 384, xbuf + (size_t)c * CM * 128, 128, 384,
                         (const float*)nullptr, (bf16*)nullptr);
    }

    // --- attention scatter ---
    hipLaunchKernelGGL(logits_k, dim3(WLN / 32), dim3(256), 0, stream, xbuf, logit_w, logit_b, ebuf);
    hipMemsetAsync(menc, 0, (size_t)NNODES * 8 * 4, stream);
    hipMemsetAsync(denomb, 0, (size_t)NNODES * 8 * 4, stream);
    hipMemsetAsync(node_emb, 0, (size_t)NNODES * 128 * 4, stream);
    hipLaunchKernelGGL(segmax_k, dim3(WLN * 8 / 256), dim3(256), 0, stream, ebuf, seg, menc);
    hipLaunchKernelGGL(expdenom_k, dim3(WLN * 8 / 256), dim3(256), 0, stream, ebuf, seg, menc, denomb);
    hipLaunchKernelGGL(tonode_scatter_k, dim3(WLN / 64, 2), dim3(256), 0, stream,
                       xbuf, to_node_w, to_node_b, ebuf, denomb, seg, node_emb);
    if (it == 0) {
      // back-projection only needed to feed iter-2 (iter-2's is dead code: head uses node_emb)
      hipLaunchKernelGGL((gemm_k<EPI_STORE>), dim3((NNODES + 63) / 64, 2), dim3(256), 0, stream,
                         node_emb, 128, from_node_w, 128, from_node_b, backb, 128, NNODES, 128, 128);
    }
  }

  // --- scoring head (fp32) ---
  hipLaunchKernelGGL((gemm_k<EPI_RELU>), dim3((NNODES + 63) / 64, 2), dim3(256), 0, stream,
                     node_emb, 128, head_w1, 128, head_b1, h1b, 128, NNODES, 128, 128);
  hipLaunchKernelGGL((gemm_k<EPI_RELU>), dim3((NNODES + 63) / 64, 2), dim3(256), 0, stream,
                     h1b, 128, head_w2, 128, head_b2, h2b, 128, NNODES, 128, 128);
  hipLaunchKernelGGL(head3_k, dim3((NNODES + 3) / 4), dim3(256), 0, stream, h2b, head_w3, head_b3, out, NNODES);
}

// Round 10
// 4259.659 us; speedup vs baseline: 1.3513x; 1.3513x over previous
//
#include <hip/hip_runtime.h>
#include <hip/hip_bf16.h>

#define WN 32768
#define LN 16
#define DN 128
#define WLN (WN * LN)        // 524288
#define NNODES 50000
#define FHN 384

typedef __attribute__((ext_vector_type(8))) short short8;
typedef __attribute__((ext_vector_type(4))) float float4v;
typedef __hip_bfloat16 bf16;

__device__ __forceinline__ unsigned fenc(float f) {
  unsigned u = __float_as_uint(f);
  return (u & 0x80000000u) ? ~u : (u | 0x80000000u);
}
__device__ __forceinline__ float fdec(unsigned u) {
  unsigned v = (u & 0x80000000u) ? (u & 0x7FFFFFFFu) : ~u;
  return __uint_as_float(v);
}
// fast transcendentals: v_exp + v_rcp (~1e-5 rel err, far below bf16 granularity)
__device__ __forceinline__ float sigm(float x) {
  return __builtin_amdgcn_rcpf(1.f + __expf(-x));
}
__device__ __forceinline__ float ftanh(float x) {
  return 1.f - 2.f * __builtin_amdgcn_rcpf(1.f + __expf(2.f * x));
}

// ---------- weight prep ----------
// Wcat2 [512][256]: rows 0..127 r:[wi|wh], 128..255 z:[wi|wh], 256..383 xn:[wi|0], 384..511 hn:[0|wh]
__global__ __launch_bounds__(256) void wcat2_k(const float* __restrict__ wi,
                                               const float* __restrict__ wh,
                                               bf16* __restrict__ W) {
  int idx = blockIdx.x * 256 + threadIdx.x;  // 512*256
  int n2 = idx >> 8, k2 = idx & 255;
  float v;
  if (n2 < 256)      v = (k2 < 128) ? wi[n2 * 128 + k2] : wh[n2 * 128 + (k2 - 128)];
  else if (n2 < 384) v = (k2 < 128) ? wi[n2 * 128 + k2] : 0.f;
  else               v = (k2 < 128) ? 0.f : wh[(n2 - 128) * 128 + (k2 - 128)];
  W[idx] = (bf16)v;
}

__global__ __launch_bounds__(256) void conv2d_k(const float* __restrict__ src, int ld,
                                                bf16* __restrict__ dst, int cols, int total) {
  int idx = blockIdx.x * 256 + threadIdx.x;
  if (idx >= total) return;
  int r = idx / cols, c = idx - r * cols;
  dst[idx] = (bf16)src[(size_t)r * ld + c];
}

// ---------- CSR build (seg constant across iterations; built once) ----------
__global__ __launch_bounds__(256) void hist_k(const int* __restrict__ seg,
                                              unsigned* __restrict__ cnt) {
  long i = (long)blockIdx.x * 256 + threadIdx.x;
  atomicAdd(&cnt[seg[i]], 1u);
}

__global__ __launch_bounds__(1024) void scan_k(const unsigned* __restrict__ cnt,
                                               unsigned* __restrict__ off) {
  __shared__ unsigned sums[1024];
  const int tid = threadIdx.x;
  const int CH = (NNODES + 1023) / 1024;  // 49
  const int base = tid * CH;
  unsigned s = 0;
  for (int j = 0; j < CH; ++j) {
    int p = base + j;
    if (p < NNODES) s += cnt[p];
  }
  sums[tid] = s;
  __syncthreads();
  for (int o = 1; o < 1024; o <<= 1) {
    unsigned t = (tid >= o) ? sums[tid - o] : 0u;
    __syncthreads();
    sums[tid] += t;
    __syncthreads();
  }
  unsigned run = (tid > 0) ? sums[tid - 1] : 0u;
  for (int j = 0; j < CH; ++j) {
    int p = base + j;
    if (p < NNODES) { off[p] = run; run += cnt[p]; }
  }
  if (tid == 1023) off[NNODES] = sums[1023];
}

__global__ __launch_bounds__(256) void fill_k(const int* __restrict__ seg,
                                              unsigned* __restrict__ cursor,
                                              int* __restrict__ idx) {
  long i = (long)blockIdx.x * 256 + threadIdx.x;
  unsigned p = atomicAdd(&cursor[seg[i]], 1u);
  idx[p] = (int)i;
}

// ---------- RMSNorm -> bf16 ----------
__global__ __launch_bounds__(256) void rmsnorm_bf16_k(const float* __restrict__ X,
                                                      const float* __restrict__ w,
                                                      bf16* __restrict__ out) {
  long row = (long)blockIdx.x * 4 + (threadIdx.x >> 6);
  int lane = threadIdx.x & 63;
  const float* x = X + row * 128;
  float v0 = x[lane], v1 = x[lane + 64];
  float ss = v0 * v0 + v1 * v1;
#pragma unroll
  for (int off = 32; off > 0; off >>= 1) ss += __shfl_down(ss, off);
  ss = __shfl(ss, 0);
  float r = rsqrtf(ss * (1.f / 128.f) + 1e-5f);
  out[row * 128 + lane] = (bf16)(v0 * r * w[lane]);
  out[row * 128 + lane + 64] = (bf16)(v1 * r * w[lane + 64]);
}

// ---------- fused gather-add + RMSNorm (iter-2 boundary) ----------
__global__ __launch_bounds__(256) void rmsnorm_gather_k(float* __restrict__ X,
                                                        const float* __restrict__ back,
                                                        const int* __restrict__ seg,
                                                        const float* __restrict__ w,
                                                        bf16* __restrict__ out) {
  long row = (long)blockIdx.x * 4 + (threadIdx.x >> 6);
  int lane = threadIdx.x & 63;
  int s = seg[row];
  float v0 = X[row * 128 + lane] + back[(long)s * 128 + lane];
  float v1 = X[row * 128 + lane + 64] + back[(long)s * 128 + lane + 64];
  X[row * 128 + lane] = v0;
  X[row * 128 + lane + 64] = v1;
  float ss = v0 * v0 + v1 * v1;
#pragma unroll
  for (int off = 32; off > 0; off >>= 1) ss += __shfl_down(ss, off);
  ss = __shfl(ss, 0);
  float r = rsqrtf(ss * (1.f / 128.f) + 1e-5f);
  out[row * 128 + lane] = (bf16)(v0 * r * w[lane]);
  out[row * 128 + lane + 64] = (bf16)(v1 * r * w[lane + 64]);
}

// ---------- persistent GRU scan: one launch runs all 16 timesteps ----------
// 512 thr = 8 waves; block owns 64 walks; state lives in LDS; B lives in VGPRs.
// Wave w, j in 0..3: column-tile ct = w + 8*j -> gate j (r,z,xn,hn), cols d = w*16 + (lane&15).
// Gate xn only uses k<128 (x part); hn only k>=128 (h part) -> those MFMAs are pruned.
__global__ __launch_bounds__(512, 2) void gru_seq_k(const bf16* __restrict__ hbase,  // [WLN][128]
                                                    bf16* __restrict__ yhist,        // [WLN][128]
                                                    const bf16* __restrict__ W,      // [512][256]
                                                    const float* __restrict__ bi,
                                                    const float* __restrict__ bh,
                                                    int reverse) {
  __shared__ __attribute__((aligned(16))) bf16 Ac[64][280];   // cols 0..127 x(t), 128..255 h, pad->2-way banks
  __shared__ __attribute__((aligned(16))) bf16 Bst[512][40];  // preamble staging only
  const int tid = threadIdx.x;
  const int w = tid >> 6, lane = tid & 63;
  const int c = lane & 15, qd = lane >> 4;
  const long rb = (long)blockIdx.x * 64;

  // ---- preload B fragments into registers (skip structurally-zero blocks) ----
  short8 breg[4][8];
#pragma unroll
  for (int kc = 0; kc < 8; ++kc) {
#pragma unroll
    for (int i = 0; i < 8; i++) {
      int q = tid + i * 512;
      int row = q >> 3, kq = (q & 7) * 4;
      *(ushort4*)&Bst[row][kq] = *(const ushort4*)(W + (size_t)row * 256 + kc * 32 + kq);
    }
    __syncthreads();
#pragma unroll
    for (int j = 0; j < 4; j++) {
      if ((j == 2 && kc >= 4) || (j == 3 && kc < 4)) continue;  // zero blocks
      breg[j][kc] = *(const short8*)&Bst[(w + 8 * j) * 16 + c][qd * 8];
    }
    __syncthreads();
  }

  // per-thread fixed output column d and its biases
  const int d = w * 16 + c;
  const float bR  = bi[d] + bh[d];
  const float bZ  = bi[128 + d] + bh[128 + d];
  const float bXN = bi[256 + d];
  const float bHN = bh[256 + d];

  // zero the state region
#pragma unroll
  for (int i = 0; i < 4; i++) {
    int q = tid + i * 512;
    int row = q >> 5, kq = (q & 31) * 4;
    *(ushort4*)&Ac[row][128 + kq] = make_ushort4(0, 0, 0, 0);
  }

  int lprev = 0;
  for (int t = 0; t < 16; ++t) {
    const int l = reverse ? (15 - t) : t;
    // stage x(l) into Ac[.][0..127]
#pragma unroll
    for (int i = 0; i < 4; i++) {
      int q = tid + i * 512;
      int row = q >> 5, kq = (q & 31) * 4;
      *(ushort4*)&Ac[row][kq] =
          *(const ushort4*)(hbase + ((rb + row) * 16 + l) * 128 + kq);
    }
    __syncthreads();
    // coalesced dump of previous step's hidden state (overlaps with MFMA below)
    if (t > 0) {
#pragma unroll
      for (int i = 0; i < 4; i++) {
        int q = tid + i * 512;
        int row = q >> 5, kq = (q & 31) * 4;
        *(ushort4*)(yhist + ((rb + row) * 16 + lprev) * 128 + kq) =
            *(const ushort4*)&Ac[row][128 + kq];
      }
    }
    float4v acc[4][4];
#pragma unroll
    for (int rt = 0; rt < 4; rt++)
#pragma unroll
      for (int j = 0; j < 4; j++) acc[rt][j] = (float4v)(0.f);
#pragma unroll
    for (int kc = 0; kc < 8; ++kc) {
      const int k0 = kc * 32;
      short8 af[4];
#pragma unroll
      for (int rt = 0; rt < 4; rt++)
        af[rt] = *(const short8*)&Ac[rt * 16 + c][k0 + qd * 8];
#pragma unroll
      for (int rt = 0; rt < 4; rt++) {
#pragma unroll
        for (int j = 0; j < 4; j++) {
          if ((j == 2 && kc >= 4) || (j == 3 && kc < 4)) continue;
          acc[rt][j] = __builtin_amdgcn_mfma_f32_16x16x32_bf16(af[rt], breg[j][kc], acc[rt][j], 0, 0, 0);
        }
      }
    }
    __syncthreads();
    // epilogue: gates -> new state (per-thread-private (row,d) cells)
#pragma unroll
    for (int rt = 0; rt < 4; rt++) {
#pragma unroll
      for (int reg = 0; reg < 4; ++reg) {
        int row = rt * 16 + qd * 4 + reg;
        float r = sigm(acc[rt][0][reg] + bR);
        float z = sigm(acc[rt][1][reg] + bZ);
        float n = ftanh(acc[rt][2][reg] + bXN + r * (acc[rt][3][reg] + bHN));
        float hold = (float)Ac[row][128 + d];
        Ac[row][128 + d] = (bf16)((1.f - z) * n + z * hold);
      }
    }
    lprev = l;
  }
  __syncthreads();
  // dump final step
#pragma unroll
  for (int i = 0; i < 4; i++) {
    int q = tid + i * 512;
    int row = q >> 5, kq = (q & 31) * 4;
    *(ushort4*)(yhist + ((rb + row) * 16 + lprev) * 128 + kq) =
        *(const ushort4*)&Ac[row][128 + kq];
  }
}

// ---------- generic bf16 MFMA GEMM: C[M,128-panel] (+)= A@B^T ----------
// EPI: 0=store, 2=add, 3=add + fused RMSNorm->bf16 (requires grid.y==1, ldc==128)
template <int EPI>
__global__ __launch_bounds__(256, 2) void mm_bf16_k(const bf16* __restrict__ A, int lda,
                                                    const bf16* __restrict__ B, int ldb,
                                                    float* __restrict__ C, int ldc, int K,
                                                    const float* __restrict__ nw,
                                                    bf16* __restrict__ hout) {
  __shared__ __attribute__((aligned(16))) bf16 As[64][40];
  __shared__ __attribute__((aligned(16))) bf16 Bs[128][40];
  const int tid = threadIdx.x;
  const int wave = tid >> 6, lane = tid & 63;
  const long rb = (long)blockIdx.x * 64;
  const int nb = blockIdx.y * 128;
  float4v acc[8];
#pragma unroll
  for (int i = 0; i < 8; i++) acc[i] = (float4v)(0.f);
  for (int k0 = 0; k0 < K; k0 += 32) {
#pragma unroll
    for (int i = 0; i < 2; i++) {
      int q = tid + i * 256;
      int row = q >> 3, kq = (q & 7) * 4;
      *(ushort4*)&As[row][kq] = *(const ushort4*)(A + (rb + row) * (size_t)lda + k0 + kq);
    }
#pragma unroll
    for (int i = 0; i < 4; i++) {
      int q = tid + i * 256;
      int row = q >> 3, kq = (q & 7) * 4;
      *(ushort4*)&Bs[row][kq] = *(const ushort4*)(B + (size_t)(nb + row) * ldb + k0 + kq);
    }
    __syncthreads();
    short8 af = *(const short8*)&As[wave * 16 + (lane & 15)][(lane >> 4) * 8];
#pragma unroll
    for (int ct = 0; ct < 8; ++ct) {
      short8 bf = *(const short8*)&Bs[ct * 16 + (lane & 15)][(lane >> 4) * 8];
      acc[ct] = __builtin_amdgcn_mfma_f32_16x16x32_bf16(af, bf, acc[ct], 0, 0, 0);
    }
    __syncthreads();
  }
  const int c = lane & 15, qd = lane >> 4;
  if (EPI == 3) {
#pragma unroll
    for (int reg = 0; reg < 4; ++reg) {
      long row = rb + wave * 16 + qd * 4 + reg;
      float v[8];
      float ssq = 0.f;
#pragma unroll
      for (int ct = 0; ct < 8; ++ct) {
        int n = ct * 16 + c;
        v[ct] = C[row * 128 + n] + acc[ct][reg];
        ssq += v[ct] * v[ct];
      }
      ssq += __shfl_xor(ssq, 1);
      ssq += __shfl_xor(ssq, 2);
      ssq += __shfl_xor(ssq, 4);
      ssq += __shfl_xor(ssq, 8);
      float rr = rsqrtf(ssq * (1.f / 128.f) + 1e-5f);
#pragma unroll
      for (int ct = 0; ct < 8; ++ct) {
        int n = ct * 16 + c;
        C[row * 128 + n] = v[ct];
        hout[row * 128 + n] = (bf16)(v[ct] * rr * nw[n]);
      }
    }
  } else {
#pragma unroll
    for (int ct = 0; ct < 8; ++ct) {
      int n = nb + ct * 16 + c;
#pragma unroll
      for (int reg = 0; reg < 4; ++reg) {
        long row = rb + wave * 16 + qd * 4 + reg;
        if (EPI == 2) C[row * ldc + n] += acc[ct][reg];
        else C[row * ldc + n] = acc[ct][reg];
      }
    }
  }
}

// ---------- to_node GEMM: V[WLN][128](bf16) = bf16(X) @ Wtn^T, no bias ----------
__global__ __launch_bounds__(256, 2) void tonode_mm_k(const float* __restrict__ A,  // [WLN][128] fp32
                                                      const bf16* __restrict__ B,   // [128][128]
                                                      bf16* __restrict__ V) {
  __shared__ __attribute__((aligned(16))) bf16 As[64][40];
  __shared__ __attribute__((aligned(16))) bf16 Bs[128][40];
  const int tid = threadIdx.x;
  const int wave = tid >> 6, lane = tid & 63;
  const long rb = (long)blockIdx.x * 64;
  float4v acc[8];
#pragma unroll
  for (int i = 0; i < 8; i++) acc[i] = (float4v)(0.f);
  for (int k0 = 0; k0 < 128; k0 += 32) {
    // stage A: 64x32 fp32 -> bf16 (512 float4 loads, 2/thread)
#pragma unroll
    for (int i = 0; i < 2; i++) {
      int q = tid + i * 256;
      int row = q >> 3, kq = (q & 7) * 4;
      float4 f = *(const float4*)(A + (rb + row) * 128 + k0 + kq);
      bf16 t4[4] = {(bf16)f.x, (bf16)f.y, (bf16)f.z, (bf16)f.w};
      *(ushort4*)&As[row][kq] = *(const ushort4*)t4;
    }
#pragma unroll
    for (int i = 0; i < 4; i++) {
      int q = tid + i * 256;
      int row = q >> 3, kq = (q & 7) * 4;
      *(ushort4*)&Bs[row][kq] = *(const ushort4*)(B + (size_t)row * 128 + k0 + kq);
    }
    __syncthreads();
    short8 af = *(const short8*)&As[wave * 16 + (lane & 15)][(lane >> 4) * 8];
#pragma unroll
    for (int ct = 0; ct < 8; ++ct) {
      short8 bf = *(const short8*)&Bs[ct * 16 + (lane & 15)][(lane >> 4) * 8];
      acc[ct] = __builtin_amdgcn_mfma_f32_16x16x32_bf16(af, bf, acc[ct], 0, 0, 0);
    }
    __syncthreads();
  }
  const int c = lane & 15, qd = lane >> 4;
#pragma unroll
  for (int ct = 0; ct < 8; ++ct) {
    int n = ct * 16 + c;
#pragma unroll
    for (int reg = 0; reg < 4; ++reg) {
      long row = rb + wave * 16 + qd * 4 + reg;
      V[row * 128 + n] = (bf16)acc[ct][reg];
    }
  }
}

// ---------- CSR gather: node_emb[s][d] = (sum e*v + bias*sum e) / (denom+1e-9) ----------
__global__ __launch_bounds__(128) void gather_k(const bf16* __restrict__ V,
                                                const float* __restrict__ e,
                                                const float* __restrict__ denom,
                                                const float* __restrict__ bias,
                                                const unsigned* __restrict__ off,
                                                const int* __restrict__ idx,
                                                float* __restrict__ node_emb) {
  const int s = blockIdx.x;
  const int d = threadIdx.x;
  const int hh = d >> 4;
  const unsigned beg = off[s], end = off[s + 1];
  float accv = 0.f, accw = 0.f;
  for (unsigned p = beg; p < end; ++p) {
    long i = idx[p];
    float w = e[i * 8 + hh];
    accv = fmaf(w, (float)V[i * 128 + d], accv);
    accw += w;
  }
  float dn = denom[(long)s * 8 + hh] + 1e-9f;
  node_emb[(long)s * 128 + d] = (accv + accw * bias[d]) / dn;
}

// ---------- fused SwiGLU gate (bf16 MFMA): U = silu(A@W1^T)*(A@W3^T) ----------
__global__ __launch_bounds__(256, 2) void ffn_gate2_k(const bf16* __restrict__ A,
                                                      const bf16* __restrict__ W13,
                                                      bf16* __restrict__ U) {
  __shared__ __attribute__((aligned(16))) bf16 As[64][40];
  __shared__ __attribute__((aligned(16))) bf16 Bs[256][40];
  const int tid = threadIdx.x;
  const int wave = tid >> 6, lane = tid & 63;
  const long rb = (long)blockIdx.x * 64;
  const int nb = blockIdx.y * 128;
  float4v a1[8], a3[8];
#pragma unroll
  for (int i = 0; i < 8; i++) { a1[i] = (float4v)(0.f); a3[i] = (float4v)(0.f); }
  for (int k0 = 0; k0 < 128; k0 += 32) {
#pragma unroll
    for (int i = 0; i < 2; i++) {
      int q = tid + i * 256;
      int row = q >> 3, kq = (q & 7) * 4;
      *(ushort4*)&As[row][kq] = *(const ushort4*)(A + (rb + row) * 128 + k0 + kq);
    }
#pragma unroll
    for (int i = 0; i < 8; i++) {
      int q = tid + i * 256;
      int row = q >> 3, kq = (q & 7) * 4;
      int srcrow = (row < 128) ? (nb + row) : (384 + nb + row - 128);
      *(ushort4*)&Bs[row][kq] = *(const ushort4*)(W13 + (size_t)srcrow * 128 + k0 + kq);
    }
    __syncthreads();
    short8 af = *(const short8*)&As[wave * 16 + (lane & 15)][(lane >> 4) * 8];
#pragma unroll
    for (int ct = 0; ct < 8; ++ct) {
      short8 b1 = *(const short8*)&Bs[ct * 16 + (lane & 15)][(lane >> 4) * 8];
      a1[ct] = __builtin_amdgcn_mfma_f32_16x16x32_bf16(af, b1, a1[ct], 0, 0, 0);
      short8 b3 = *(const short8*)&Bs[128 + ct * 16 + (lane & 15)][(lane >> 4) * 8];
      a3[ct] = __builtin_amdgcn_mfma_f32_16x16x32_bf16(af, b3, a3[ct], 0, 0, 0);
    }
    __syncthreads();
  }
  const int c = lane & 15, qd = lane >> 4;
#pragma unroll
  for (int ct = 0; ct < 8; ++ct) {
    int d = nb + ct * 16 + c;
#pragma unroll
    for (int reg = 0; reg < 4; ++reg) {
      long row = rb + wave * 16 + qd * 4 + reg;
      float g = a1[ct][reg];
      U[row * 384 + d] = (bf16)(g * sigm(g) * a3[ct][reg]);
    }
  }
}

// ---------- fp32 GEMM (precision-critical small paths) ----------
enum { EPI_STORE = 0, EPI_RELU = 1 };
template <int EPI>
__global__ __launch_bounds__(256) void gemm_k(const float* __restrict__ A, int lda,
                                              const float* __restrict__ B, int ldb,
                                              const float* __restrict__ bias,
                                              float* __restrict__ C, int ldc,
                                              int M, int N, int K) {
  __shared__ float As[16][68];
  __shared__ float Bs[16][68];
  const int tid = threadIdx.x;
  const int bm = blockIdx.x * 64;
  const int bn = blockIdx.y * 64;
  const int lm = tid >> 2;
  const int lk = (tid & 3) << 2;
  const int tm = (tid >> 4) << 2;
  const int tn = (tid & 15) << 2;
  float acc[4][4] = {};
  for (int k0 = 0; k0 < K; k0 += 16) {
    float4 av = make_float4(0.f, 0.f, 0.f, 0.f);
    if (bm + lm < M)
      av = *reinterpret_cast<const float4*>(A + (long)(bm + lm) * lda + k0 + lk);
    As[lk + 0][lm] = av.x; As[lk + 1][lm] = av.y; As[lk + 2][lm] = av.z; As[lk + 3][lm] = av.w;
    float4 bv = *reinterpret_cast<const float4*>(B + (long)(bn + lm) * ldb + k0 + lk);
    Bs[lk + 0][lm] = bv.x; Bs[lk + 1][lm] = bv.y; Bs[lk + 2][lm] = bv.z; Bs[lk + 3][lm] = bv.w;
    __syncthreads();
#pragma unroll
    for (int k = 0; k < 16; k++) {
      float a[4], b[4];
#pragma unroll
      for (int j = 0; j < 4; j++) { a[j] = As[k][tm + j]; b[j] = Bs[k][tn + j]; }
#pragma unroll
      for (int i = 0; i < 4; i++)
#pragma unroll
        for (int j = 0; j < 4; j++) acc[i][j] = fmaf(a[i], b[j], acc[i][j]);
    }
    __syncthreads();
  }
#pragma unroll
  for (int i = 0; i < 4; i++) {
    int gm = bm + tm + i;
    if (gm < M) {
      float* crow = C + (long)gm * ldc + bn;
#pragma unroll
      for (int j = 0; j < 4; j++) {
        float v = acc[i][j] + (bias ? bias[bn + tn + j] : 0.f);
        if (EPI == EPI_RELU) v = fmaxf(v, 0.f);
        crow[tn + j] = v;
      }
    }
  }
}

// ---------- attention pointwise ----------
__global__ __launch_bounds__(256) void logits_k(const float* __restrict__ X,
                                                const float* __restrict__ LW,
                                                const float* __restrict__ LB,
                                                float* __restrict__ out) {
  __shared__ float w[1024];
  __shared__ float b[8];
  int tid = threadIdx.x;
  for (int i = tid; i < 1024; i += 256) w[i] = LW[i];
  if (tid < 8) b[tid] = LB[tid];
  __syncthreads();
  long r = (long)blockIdx.x * 32 + (tid >> 3);
  int hh = tid & 7;
  const float* x = X + r * 128;
  const float* wr = w + hh * 128;
  float s = 0.f;
#pragma unroll 16
  for (int k = 0; k < 128; k++) s = fmaf(x[k], wr[k], s);
  out[r * 8 + hh] = s + b[hh];
}

__global__ __launch_bounds__(256) void segmax_k(const float* __restrict__ logits,
                                                const int* __restrict__ seg,
                                                unsigned* __restrict__ menc) {
  long idx = (long)blockIdx.x * 256 + threadIdx.x;
  long i = idx >> 3;
  int hh = idx & 7;
  atomicMax(&menc[(long)seg[i] * 8 + hh], fenc(logits[idx]));
}

__global__ __launch_bounds__(256) void expdenom_k(float* __restrict__ e_or_logits,
                                                  const int* __restrict__ seg,
                                                  const unsigned* __restrict__ menc,
                                                  float* __restrict__ denom) {
  long idx = (long)blockIdx.x * 256 + threadIdx.x;
  long i = idx >> 3;
  int hh = idx & 7;
  int s = seg[i];
  float ev = expf(e_or_logits[idx] - fdec(menc[(long)s * 8 + hh]));
  e_or_logits[idx] = ev;
  atomicAdd(&denom[(long)s * 8 + hh], ev);
}

__global__ __launch_bounds__(256) void head3_k(const float* __restrict__ H2,
                                               const float* __restrict__ W3,
                                               const float* __restrict__ B3,
                                               float* __restrict__ out, int M) {
  int row = blockIdx.x * 4 + (threadIdx.x >> 6);
  int lane = threadIdx.x & 63;
  if (row >= M) return;
  const float* x = H2 + (long)row * 128;
  float s = x[lane] * W3[lane] + x[lane + 64] * W3[lane + 64];
#pragma unroll
  for (int off = 32; off > 0; off >>= 1) s += __shfl_down(s, off);
  if (lane == 0) out[row] = s + B3[0];
}

// ---------- host ----------
extern "C" void kernel_launch(void* const* d_in, const int* in_sizes, int n_in,
                              void* d_out, int out_size, void* d_ws, size_t ws_size,
                              hipStream_t stream) {
  (void)in_sizes; (void)n_in; (void)out_size; (void)ws_size;
  const float* in_x       = (const float*)d_in[0];
  const int*   seg        = (const int*)d_in[1];
  const float* gru_norm_w = (const float*)d_in[3];
  const float* wi_f       = (const float*)d_in[4];
  const float* wh_f       = (const float*)d_in[5];
  const float* bi_f       = (const float*)d_in[6];
  const float* bh_f       = (const float*)d_in[7];
  const float* wi_b       = (const float*)d_in[8];
  const float* wh_b       = (const float*)d_in[9];
  const float* bi_b       = (const float*)d_in[10];
  const float* bh_b       = (const float*)d_in[11];
  const float* gru_out_w  = (const float*)d_in[12];
  const float* ffn_norm_w = (const float*)d_in[13];
  const float* ffn_w1     = (const float*)d_in[14];
  const float* ffn_w2     = (const float*)d_in[15];
  const float* ffn_w3     = (const float*)d_in[16];
  const float* logit_w    = (const float*)d_in[17];
  const float* logit_b    = (const float*)d_in[18];
  const float* to_node_w  = (const float*)d_in[19];
  const float* to_node_b  = (const float*)d_in[20];
  const float* from_node_w= (const float*)d_in[21];
  const float* from_node_b= (const float*)d_in[22];
  const float* head_w1    = (const float*)d_in[23];
  const float* head_b1    = (const float*)d_in[24];
  const float* head_w2    = (const float*)d_in[25];
  const float* head_b2    = (const float*)d_in[26];
  const float* head_w3    = (const float*)d_in[27];
  const float* head_b3    = (const float*)d_in[28];
  float* out = (float*)d_out;

  // ---- workspace carve-up (float slots), ~592 MB total ----
  float* ws = (float*)d_ws;
  size_t o = 0;
  auto alloc = [&](size_t n) { float* p = ws + o; o += (n + 63) & ~(size_t)63; return p; };
  float* xbuf = alloc((size_t)WLN * 128);   // 268.4 MB fp32 x
  bf16*  hb16 = (bf16*)alloc((size_t)WLN * 64); // 134.2 MB bf16 normed-x; dead during attention -> vbuf alias
  float* pool = alloc((size_t)WLN * 64);    // 134.2 MB time-shared pool
  // pool phase A (GRU): yhist [WLN][128] bf16
  bf16* yhist = (bf16*)pool;
  // pool phase B (FFN+attention): ub16 | ebuf | menc | denomb
  bf16*     ub16   = (bf16*)pool;                               // 65536*384 bf16 = 50.3 MB
  float*    ebuf   = pool + (size_t)65536 * 384 / 2;            // WLN*8 fp32
  unsigned* menc   = (unsigned*)(ebuf + (size_t)WLN * 8);       // NNODES*8
  float*    denomb = (float*)(menc + (size_t)NNODES * 8);       // NNODES*8
  // pool phase C (post-loop head): h1b | h2b
  float* h1b = pool;
  float* h2b = pool + (size_t)NNODES * 128;
  // vbuf aliases hb16 during attention (hb16's last read is ffn_gate2_k)
  bf16* vbuf = hb16;
  float* node_emb = alloc((size_t)NNODES * 128);  // survives into head
  float* backb    = alloc((size_t)NNODES * 128);  // survives it0->it1 boundary
  bf16* Wcat2_f = (bf16*)alloc(512 * 256 / 2);
  bf16* Wcat2_b = (bf16*)alloc(512 * 256 / 2);
  bf16* WoF     = (bf16*)alloc(128 * 128 / 2);
  bf16* WoB     = (bf16*)alloc(128 * 128 / 2);
  bf16* W13     = (bf16*)alloc(768 * 128 / 2);
  bf16* W2b     = (bf16*)alloc(128 * 384 / 2);
  bf16* Wtn     = (bf16*)alloc(128 * 128 / 2);
  unsigned* cntb = (unsigned*)alloc(NNODES);
  unsigned* offb = (unsigned*)alloc(NNODES + 1);
  unsigned* curb = (unsigned*)alloc(NNODES + 1);
  int*      idxb = (int*)alloc(WLN);

  // ---- weight conversion ----
  hipLaunchKernelGGL(wcat2_k, dim3(512), dim3(256), 0, stream, wi_f, wh_f, Wcat2_f);
  hipLaunchKernelGGL(wcat2_k, dim3(512), dim3(256), 0, stream, wi_b, wh_b, Wcat2_b);
  hipLaunchKernelGGL(conv2d_k, dim3(64), dim3(256), 0, stream, gru_out_w, 256, WoF, 128, 128 * 128);
  hipLaunchKernelGGL(conv2d_k, dim3(64), dim3(256), 0, stream, gru_out_w + 128, 256, WoB, 128, 128 * 128);
  hipLaunchKernelGGL(conv2d_k, dim3(192), dim3(256), 0, stream, ffn_w1, 128, W13, 128, 384 * 128);
  hipLaunchKernelGGL(conv2d_k, dim3(192), dim3(256), 0, stream, ffn_w3, 128, W13 + 384 * 128, 128, 384 * 128);
  hipLaunchKernelGGL(conv2d_k, dim3(192), dim3(256), 0, stream, ffn_w2, 384, W2b, 384, 128 * 384);
  hipLaunchKernelGGL(conv2d_k, dim3(64), dim3(256), 0, stream, to_node_w, 128, Wtn, 128, 128 * 128);

  // ---- CSR of walk-positions per node (seg constant across iterations) ----
  hipMemsetAsync(cntb, 0, (size_t)NNODES * 4, stream);
  hipLaunchKernelGGL(hist_k, dim3(WLN / 256), dim3(256), 0, stream, seg, cntb);
  hipLaunchKernelGGL(scan_k, dim3(1), dim3(1024), 0, stream, cntb, offb);
  hipMemcpyAsync(curb, offb, (size_t)NNODES * 4, hipMemcpyDeviceToDevice, stream);
  hipLaunchKernelGGL(fill_k, dim3(WLN / 256), dim3(256), 0, stream, seg, curb, idxb);

  hipMemcpyAsync(xbuf, in_x, (size_t)WLN * 128 * 4, hipMemcpyDeviceToDevice, stream);

  for (int it = 0; it < 2; ++it) {
    // --- GRU block: RMSNorm (iter-2: fused gather-add of prior back-projection) ---
    if (it == 0)
      hipLaunchKernelGGL(rmsnorm_bf16_k, dim3(WLN / 4), dim3(256), 0, stream, xbuf, gru_norm_w, hb16);
    else
      hipLaunchKernelGGL(rmsnorm_gather_k, dim3(WLN / 4), dim3(256), 0, stream, xbuf, backb, seg, gru_norm_w, hb16);
    // persistent scan, forward; then deferred output projection
    hipLaunchKernelGGL(gru_seq_k, dim3(WN / 64), dim3(512), 0, stream,
                       hb16, yhist, Wcat2_f, bi_f, bh_f, 0);
    hipLaunchKernelGGL((mm_bf16_k<2>), dim3(WLN / 64, 1), dim3(256), 0, stream,
                       yhist, 128, WoF, 128, xbuf, 128, 128, (const float*)nullptr, (bf16*)nullptr);
    // backward scan; projection fused with FFN RMSNorm
    hipLaunchKernelGGL(gru_seq_k, dim3(WN / 64), dim3(512), 0, stream,
                       hb16, yhist, Wcat2_b, bi_b, bh_b, 1);
    hipLaunchKernelGGL((mm_bf16_k<3>), dim3(WLN / 64, 1), dim3(256), 0, stream,
                       yhist, 128, WoB, 128, xbuf, 128, 128, ffn_norm_w, hb16);

    // --- FFN (8 chunks of 65536 rows) ---
    for (int c = 0; c < 8; ++c) {
      const int CM = WLN / 8;
      hipLaunchKernelGGL(ffn_gate2_k, dim3(CM / 64, 3), dim3(256), 0, stream,
                         hb16 + (size_t)c * CM * 128, W13, ub16);
      hipLaunchKernelGGL((mm_bf16_k<2>), dim3(CM / 64, 1), dim3(256), 0, stream,
                         ub16, 384, W2b, 384, xbuf + (size_t)c * CM * 128, 128, 384,
                         (const float*)nullptr, (bf16*)nullptr);
    }

    // --- attention: softmax weights, then CSR gather (no atomics on node_emb) ---
    hipLaunchKernelGGL(logits_k, dim3(WLN / 32), dim3(256), 0, stream, xbuf, logit_w, logit_b, ebuf);
    hipMemsetAsync(menc, 0, (size_t)NNODES * 8 * 4, stream);
    hipMemsetAsync(denomb, 0, (size_t)NNODES * 8 * 4, stream);
    hipLaunchKernelGGL(segmax_k, dim3(WLN * 8 / 256), dim3(256), 0, stream, ebuf, seg, menc);
    hipLaunchKernelGGL(expdenom_k, dim3(WLN * 8 / 256), dim3(256), 0, stream, ebuf, seg, menc, denomb);
    hipLaunchKernelGGL(tonode_mm_k, dim3(WLN / 64), dim3(256), 0, stream, xbuf, Wtn, vbuf);
    hipLaunchKernelGGL(gather_k, dim3(NNODES), dim3(128), 0, stream,
                       vbuf, ebuf, denomb, to_node_b, offb, idxb, node_emb);
    if (it == 0) {
      // back-projection only needed to feed iter-2 (iter-2's is dead code: head uses node_emb)
      hipLaunchKernelGGL((gemm_k<EPI_STORE>), dim3((NNODES + 63) / 64, 2), dim3(256), 0, stream,
                         node_emb, 128, from_node_w, 128, from_node_b, backb, 128, NNODES, 128, 128);
    }
  }

  // --- scoring head (fp32) ---
  hipLaunchKernelGGL((gemm_k<EPI_RELU>), dim3((NNODES + 63) / 64, 2), dim3(256), 0, stream,
                     node_emb, 128, head_w1, 128, head_b1, h1b, 128, NNODES, 128, 128);
  hipLaunchKernelGGL((gemm_k<EPI_RELU>), dim3((NNODES + 63) / 64, 2), dim3(256), 0, stream,
                     h1b, 128, head_w2, 128, head_b2, h2b, 128, NNODES, 128, 128);
  hipLaunchKernelGGL(head3_k, dim3((NNODES + 3) / 4), dim3(256), 0, stream, h2b, head_w3, head_b3, out, NNODES);
}